// Round 12
// baseline (206.584 us; speedup 1.0000x reference)
//
#include <hip/hip_runtime.h>
#include <cstdint>
#include <cstddef>

#define B_ 8
#define S_ 1024
#define E_ 1024
#define H_ 16
#define D_ 64
#define M_ (B_*S_)

typedef _Float16 f16;
typedef __attribute__((ext_vector_type(8))) _Float16 f16x8;
typedef __attribute__((ext_vector_type(4))) _Float16 f16x4;
typedef __attribute__((ext_vector_type(4))) float  f32x4;
typedef __attribute__((ext_vector_type(16))) float f32x16;
typedef __attribute__((ext_vector_type(4))) int    int4v;
typedef __attribute__((ext_vector_type(2))) int    int2v;

__device__ __forceinline__ f32x4 mfma16(f16x8 a, f16x8 b, f32x4 c) {
  return __builtin_amdgcn_mfma_f32_16x16x32_f16(a, b, c, 0, 0, 0);
}
__device__ __forceinline__ f32x16 mfma32(f16x8 a, f16x8 b, f32x16 c) {
  return __builtin_amdgcn_mfma_f32_32x32x16_f16(a, b, c, 0, 0, 0);
}
__device__ __forceinline__ void gll16(const f16* g, f16* l) {
  __builtin_amdgcn_global_load_lds(
      (const __attribute__((address_space(1))) void*)g,
      (__attribute__((address_space(3))) void*)l, 16, 0, 0);
}
__device__ __forceinline__ int pkrtz(float lo, float hi) {
  return __builtin_bit_cast(int, __builtin_amdgcn_cvt_pkrtz(lo, hi));
}

// ---------------------------------------------------------------------------
// X fp32 -> fp16
// ---------------------------------------------------------------------------
__global__ __launch_bounds__(256) void presplit_kernel(
    const float* __restrict__ X, f16* __restrict__ Xf) {
  size_t i = ((size_t)blockIdx.x * 256 + threadIdx.x) * 8;
  f32x4 v0 = *(const f32x4*)&X[i];
  f32x4 v1 = *(const f32x4*)&X[i + 4];
  f16x8 hv;
#pragma unroll
  for (int j = 0; j < 4; ++j) {
    hv[j] = (f16)v0[j];
    hv[j + 4] = (f16)v1[j];
  }
  *(f16x8*)&Xf[i] = hv;
}

// ---------------------------------------------------------------------------
// Transpose + convert weights -> single fp16, [f][e] layout.
// W_Q pre-scaled by log2(e) (softmax runs in exp2 domain).
// ---------------------------------------------------------------------------
__global__ __launch_bounds__(512) void wt_conv3_kernel(
    const float* __restrict__ Wq, const float* __restrict__ Wk,
    const float* __restrict__ Wv, f16* __restrict__ oq, f16* __restrict__ ok,
    f16* __restrict__ ov) {
  const float* W = blockIdx.z == 0 ? Wq : (blockIdx.z == 1 ? Wk : Wv);
  f16* o = blockIdx.z == 0 ? oq : (blockIdx.z == 1 ? ok : ov);
  const float scl = blockIdx.z == 0 ? 1.4426950408889634f : 1.0f;
  __shared__ float t[64][65];
  const int f0 = blockIdx.x * 64, e0 = blockIdx.y * 64;
  const int tx = threadIdx.x, ty = threadIdx.y;
#pragma unroll
  for (int j = 0; j < 8; ++j)
    t[ty + 8 * j][tx] = W[(size_t)(e0 + ty + 8 * j) * E_ + f0 + tx];
  __syncthreads();
#pragma unroll
  for (int j = 0; j < 8; ++j)
    o[(size_t)(f0 + ty + 8 * j) * E_ + e0 + tx] =
        (f16)(t[tx][ty + 8 * j] * scl);
}

// ---------------------------------------------------------------------------
// Fused QKV GEMM: O = X(f16) * W(f16).  (unchanged: ~792 TF, m97 ceiling)
// z: 0-7 = Q ([B,H,S,D], log2e-scaled), 8-15 = K ([B,H,S,D]),
//    16-23 = V (transposed [B,H,D,S]).
// ---------------------------------------------------------------------------
__global__ __launch_bounds__(256) void gemm_qkv_kernel(
    const f16* __restrict__ Xf,
    const f16* __restrict__ Wq, const f16* __restrict__ Wk,
    const f16* __restrict__ Wv,
    f16* __restrict__ Qf, f16* __restrict__ Kf, f16* __restrict__ Vt) {
  __shared__ f16 sA[128][64], sB[128][64];   // 32 KB
  const int bid = blockIdx.x;
  const int xcd = bid & 7, idx = bid >> 3;   // idx in [0,192)
  const int mb = xcd * 8 + idx / 24;         // [0,64)
  const int nb = idx % 24;
  const int z = nb >> 3;
  const int n0 = (nb & 7) * 128, m0 = mb * 128;
  const f16* __restrict__ Bt = z == 0 ? Wq : (z == 1 ? Wk : Wv);
  const int tid = threadIdx.x;
  const int lane = tid & 63, w = tid >> 6;
  const int wm = (w >> 1) * 64, wn = (w & 1) * 64;
  const int fr = lane & 15, fg = lane >> 4;
  f32x4 acc[4][4] = {};
  for (int k0 = 0; k0 < E_; k0 += 64) {
#pragma unroll
    for (int i = 0; i < 4; ++i) {
      int ci = tid + i * 256;
      int r = ci >> 3, cl = ci & 7;
      int cs = (cl ^ (r & 7)) * 8;       // pre-swizzled global source column
      gll16(Xf + (size_t)(m0 + r) * E_ + k0 + cs, &sA[0][0] + ci * 8);
      gll16(Bt + (size_t)(n0 + r) * E_ + k0 + cs, &sB[0][0] + ci * 8);
    }
    __syncthreads();
#pragma unroll
    for (int kh2 = 0; kh2 < 2; ++kh2) {
      f16x8 ah[4];
#pragma unroll
      for (int mi = 0; mi < 4; ++mi) {
        int rA = wm + mi * 16 + fr;
        ah[mi] = *(const f16x8*)&sA[rA][(((kh2 * 4 + fg) ^ (rA & 7))) * 8];
      }
#pragma unroll
      for (int ni = 0; ni < 4; ++ni) {
        int rB = wn + ni * 16 + fr;
        f16x8 bh = *(const f16x8*)&sB[rB][(((kh2 * 4 + fg) ^ (rB & 7))) * 8];
#pragma unroll
        for (int mi = 0; mi < 4; ++mi)
          acc[mi][ni] = mfma16(ah[mi], bh, acc[mi][ni]);
      }
    }
    __syncthreads();
  }
  if (z < 2) {
    f16* Of = z == 0 ? Qf : Kf;
#pragma unroll
    for (int mi = 0; mi < 4; ++mi)
#pragma unroll
      for (int ni = 0; ni < 4; ++ni)
#pragma unroll
        for (int r = 0; r < 4; ++r) {
          int row = m0 + wm + mi * 16 + (lane >> 4) * 4 + r;
          int col = n0 + wn + ni * 16 + fr;
          int bb = row >> 10, s = row & 1023;
          int hd = col >> 6, d = col & 63;
          Of[((size_t)(bb * H_ + hd) * S_ + s) * D_ + d] = (f16)acc[mi][ni][r];
        }
  } else {
#pragma unroll
    for (int mi = 0; mi < 4; ++mi)
#pragma unroll
      for (int ni = 0; ni < 4; ++ni) {
        int row = m0 + wm + mi * 16 + (lane >> 4) * 4;
        int col = n0 + wn + ni * 16 + fr;
        int bb = row >> 10, s = row & 1023;
        int hd = col >> 6, d = col & 63;
        f16x4 p;
#pragma unroll
        for (int r = 0; r < 4; ++r) p[r] = (f16)acc[mi][ni][r];
        *(f16x4*)&Vt[((size_t)(bb * H_ + hd) * D_ + d) * S_ + s] = p;
      }
  }
}

// ---------------------------------------------------------------------------
// Flash attention + ReLU — LDS-FREE / BARRIER-FREE version.
// r11 evidence: duration tracks wave concurrency, not work; the barrier-locked
// LDS pipeline stalls ~50% of cycles.  K/V per head = 256 KB and all 8
// q-blocks of a head sit on one XCD -> K/V is L2-resident.  So read K/V
// fragments DIRECTLY from global (each fragment is a 16B-contiguous dwordx4;
// no swizzle needed), delete all staging/barriers/vmcnt, and let 16
// independent waves/CU hide latency by pure TLP.  Math is bit-identical to
// r11 except rowsum is back on VALU (frees 16 VGPR of Ol to keep regs <=128).
// ---------------------------------------------------------------------------
__global__ __launch_bounds__(256) void attn_kernel(
    const f16* __restrict__ Qf, const f16* __restrict__ Kf,
    const f16* __restrict__ Vt, float* __restrict__ out) {
  const int bid = blockIdx.x;
  const int bh = (bid & 7) * 16 + (bid >> 6);    // 8 qb of one bh on one XCD
  const int qb = (bid >> 3) & 7;
  const int hd = bh & 15, bb = bh >> 4;
  const int lane = threadIdx.x & 63, w = threadIdx.x >> 6;
  const int cq = lane & 31, h = lane >> 5;
  const size_t base = (size_t)bh * (S_ * D_);
  const f16* Qp = Qf + base;
  const f16* Kp = Kf + base + (size_t)cq * D_ + 8 * h;   // lane K base
  const f16* Vp = Vt + base + (size_t)cq * S_ + 8 * h;   // lane V^T base
  const int q0 = qb * 128 + w * 32;

  f16x8 qh_[4];
#pragma unroll
  for (int ks = 0; ks < 4; ++ks)
    qh_[ks] = *(const f16x8*)&Qp[(size_t)(q0 + cq) * D_ + ks * 16 + 8 * h];

  float m_run, l_run;
  f32x16 O[2] = {};
  f16x8 pf[4];

  // K fragment: K[t*64 + f*32 + cq][ks*16 + 8h .. +8]
#define QKT(scv, t)                                                           \
  {                                                                           \
    _Pragma("unroll")                                                         \
    for (int f = 0; f < 2; ++f) {                                             \
      f16x8 kv[4];                                                            \
      _Pragma("unroll")                                                       \
      for (int ks = 0; ks < 4; ++ks)                                          \
        kv[ks] = *(const f16x8*)&Kp[((t) * 64 + f * 32) * D_ + ks * 16];      \
      __builtin_amdgcn_s_setprio(1);                                          \
      _Pragma("unroll")                                                       \
      for (int ks = 0; ks < 4; ++ks)                                          \
        scv[f] = mfma32(kv[ks], qh_[ks], scv[f]);                             \
      __builtin_amdgcn_s_setprio(0);                                          \
    }                                                                         \
  }

  // V fragment: V^T[df*32 + cq][t*64 + ks*16 + 8h .. +8]
#define LOADV(vfv, t, df)                                                     \
  {                                                                           \
    _Pragma("unroll")                                                         \
    for (int ks = 0; ks < 4; ++ks)                                            \
      vfv[ks] = *(const f16x8*)&Vp[(size_t)(df) * 32 * S_ + (t) * 64 + ks * 16]; \
  }

#define MAXTREE(pm, scv)                                                      \
  {                                                                           \
    float t4[4];                                                              \
    _Pragma("unroll")                                                         \
    for (int i = 0; i < 4; ++i) {                                             \
      float a = fmaxf(fmaxf(scv[0][i], scv[0][i + 4]),                        \
                      fmaxf(scv[0][i + 8], scv[0][i + 12]));                  \
      float b = fmaxf(fmaxf(scv[1][i], scv[1][i + 4]),                        \
                      fmaxf(scv[1][i + 8], scv[1][i + 12]));                  \
      t4[i] = fmaxf(a, b);                                                    \
    }                                                                         \
    pm = fmaxf(fmaxf(t4[0], t4[1]), fmaxf(t4[2], t4[3]));                     \
    pm = fmaxf(pm, __shfl_xor(pm, 32));                                       \
  }

#define ROWSUM(rs, scv)                                                       \
  {                                                                           \
    float rs0 = 0.f, rs1 = 0.f, rs2 = 0.f, rs3 = 0.f;                         \
    _Pragma("unroll")                                                         \
    for (int f = 0; f < 2; ++f) {                                             \
      _Pragma("unroll")                                                       \
      for (int r4 = 0; r4 < 4; ++r4) {                                        \
        rs0 += scv[f][4 * r4 + 0];                                            \
        rs1 += scv[f][4 * r4 + 1];                                            \
        rs2 += scv[f][4 * r4 + 2];                                            \
        rs3 += scv[f][4 * r4 + 3];                                            \
      }                                                                       \
    }                                                                         \
    rs = (rs0 + rs1) + (rs2 + rs3);                                           \
    rs += __shfl_xor(rs, 32);                                                 \
  }

#define PFBUILD(scv)                                                          \
  {                                                                           \
    _Pragma("unroll")                                                         \
    for (int f = 0; f < 2; ++f) {                                             \
      _Pragma("unroll")                                                       \
      for (int ksl = 0; ksl < 2; ++ksl) {                                     \
        int b0 = 8 * ksl;                                                     \
        int a1 = pkrtz(scv[f][b0 + 0], scv[f][b0 + 1]);                       \
        int b1 = pkrtz(scv[f][b0 + 4], scv[f][b0 + 5]);                       \
        int2v r1 = __builtin_amdgcn_permlane32_swap(a1, b1, false, false);    \
        int a2 = pkrtz(scv[f][b0 + 2], scv[f][b0 + 3]);                       \
        int b2 = pkrtz(scv[f][b0 + 6], scv[f][b0 + 7]);                       \
        int2v r2 = __builtin_amdgcn_permlane32_swap(a2, b2, false, false);    \
        int4v wd;                                                             \
        wd[0] = r1[0]; wd[1] = r2[0]; wd[2] = r1[1]; wd[3] = r2[1];           \
        pf[2 * f + ksl] = __builtin_bit_cast(f16x8, wd);                      \
      }                                                                       \
    }                                                                         \
  }

#define PVT(t)                                                                \
  {                                                                           \
    f16x8 vf0[4], vf1[4];                                                     \
    LOADV(vf0, t, 0);                                                         \
    LOADV(vf1, t, 1);                                                         \
    __builtin_amdgcn_s_setprio(1);                                            \
    _Pragma("unroll")                                                         \
    for (int ks = 0; ks < 4; ++ks) {                                          \
      O[0] = mfma32(vf0[ks], pf[ks], O[0]);                                   \
      O[1] = mfma32(vf1[ks], pf[ks], O[1]);                                   \
    }                                                                         \
    __builtin_amdgcn_s_setprio(0);                                            \
  }

  // ---- chunk 0: exact max path (overflow-safe)
  {
    f32x16 sc[2] = {};
    QKT(sc, 0);
    float pm;
    MAXTREE(pm, sc);
    m_run = pm;
#pragma unroll
    for (int f = 0; f < 2; ++f)
#pragma unroll
      for (int r = 0; r < 16; ++r)
        sc[f][r] = __builtin_amdgcn_exp2f(sc[f][r] - pm);
    float rs;
    ROWSUM(rs, sc);
    l_run = rs;
    PFBUILD(sc);
    PVT(0);
  }

  // ---- chunks 1..15: speculative exp vs running m + rare exact rescale
  for (int t = 1; t < 16; ++t) {
    f32x16 sc[2];
#pragma unroll
    for (int f = 0; f < 2; ++f)
#pragma unroll
      for (int r = 0; r < 16; ++r) sc[f][r] = -m_run;
    QKT(sc, t);

#pragma unroll
    for (int f = 0; f < 2; ++f)
#pragma unroll
      for (int r = 0; r < 16; ++r)
        sc[f][r] = __builtin_amdgcn_exp2f(sc[f][r]);

    float pm;
    MAXTREE(pm, sc);
    if (__any(pm > 2048.f)) {
      float pmx = fmaxf(pm, 1.0f);
      float scl = 1.0f / pmx;
      m_run += __builtin_amdgcn_logf(pmx);   // v_log_f32 = log2 (exp2 domain)
      l_run *= scl;
#pragma unroll
      for (int f = 0; f < 2; ++f)
#pragma unroll
        for (int r = 0; r < 16; ++r) sc[f][r] *= scl;
#pragma unroll
      for (int df = 0; df < 2; ++df)
#pragma unroll
        for (int i = 0; i < 16; ++i) O[df][i] *= scl;
    }

    float rs;
    ROWSUM(rs, sc);
    l_run += rs;
    PFBUILD(sc);
    PVT(t);
  }

  // ---- epilogue: relu(O/l) -> fp32 [B,S,E]
  float inv = 1.0f / l_run;
  int s = q0 + cq;
  float* orow = out + ((size_t)bb * S_ + s) * E_ + hd * 64;
#pragma unroll
  for (int df = 0; df < 2; ++df)
#pragma unroll
    for (int g = 0; g < 4; ++g) {
      f32x4 vv;
#pragma unroll
      for (int j = 0; j < 4; ++j)
        vv[j] = fmaxf(O[df][4 * g + j] * inv, 0.f);
      *(f32x4*)&orow[df * 32 + 8 * g + 4 * h] = vv;
    }
}

// ---------------------------------------------------------------------------
// Launcher. Workspace ~70 MB:
//  Wq,Wk,Wv 3x2MB @0; Xf @6M; Qf @22M; Kf @38M; Vt @54M
// ---------------------------------------------------------------------------
extern "C" void kernel_launch(void* const* d_in, const int* in_sizes, int n_in,
                              void* d_out, int out_size, void* d_ws, size_t ws_size,
                              hipStream_t stream) {
  const float* X  = (const float*)d_in[0];
  const float* Wq = (const float*)d_in[1];
  const float* Wk = (const float*)d_in[2];
  const float* Wv = (const float*)d_in[3];
  float* out = (float*)d_out;
  char* ws = (char*)d_ws;

  const size_t WSZ = (size_t)E_ * E_ * sizeof(f16);   // 2 MB
  const size_t QSZ = (size_t)M_ * E_ * sizeof(f16);   // 16 MB
  f16* Wqf = (f16*)(ws);
  f16* Wkf = (f16*)(ws + WSZ);
  f16* Wvf = (f16*)(ws + 2 * WSZ);
  char* p = ws + 3 * WSZ;
  f16* Xf = (f16*)(p);
  f16* Qf = (f16*)(p + QSZ);
  f16* Kf = (f16*)(p + 2 * QSZ);
  f16* Vt = (f16*)(p + 3 * QSZ);

  presplit_kernel<<<4096, 256, 0, stream>>>(X, Xf);
  wt_conv3_kernel<<<dim3(16, 16, 3), dim3(64, 8), 0, stream>>>(
      Wq, Wk, Wv, Wqf, Wkf, Wvf);

  gemm_qkv_kernel<<<1536, 256, 0, stream>>>(
      Xf, Wqf, Wkf, Wvf, Qf, Kf, Vt);

  attn_kernel<<<1024, 256, 0, stream>>>(Qf, Kf, Vt, out);
}

// Round 13
// 136.681 us; speedup vs baseline: 1.5114x; 1.5114x over previous
//
#include <hip/hip_runtime.h>
#include <cstdint>
#include <cstddef>

#define B_ 8
#define S_ 1024
#define E_ 1024
#define H_ 16
#define D_ 64
#define M_ (B_*S_)

typedef _Float16 f16;
typedef __attribute__((ext_vector_type(8))) _Float16 f16x8;
typedef __attribute__((ext_vector_type(4))) _Float16 f16x4;
typedef __attribute__((ext_vector_type(4))) float  f32x4;
typedef __attribute__((ext_vector_type(16))) float f32x16;
typedef __attribute__((ext_vector_type(4))) int    int4v;
typedef __attribute__((ext_vector_type(2))) int    int2v;

__device__ __forceinline__ f32x4 mfma16(f16x8 a, f16x8 b, f32x4 c) {
  return __builtin_amdgcn_mfma_f32_16x16x32_f16(a, b, c, 0, 0, 0);
}
__device__ __forceinline__ f32x16 mfma32(f16x8 a, f16x8 b, f32x16 c) {
  return __builtin_amdgcn_mfma_f32_32x32x16_f16(a, b, c, 0, 0, 0);
}
__device__ __forceinline__ void gll16(const f16* g, f16* l) {
  __builtin_amdgcn_global_load_lds(
      (const __attribute__((address_space(1))) void*)g,
      (__attribute__((address_space(3))) void*)l, 16, 0, 0);
}
__device__ __forceinline__ int pkrtz(float lo, float hi) {
  return __builtin_bit_cast(int, __builtin_amdgcn_cvt_pkrtz(lo, hi));
}

// ---------------------------------------------------------------------------
// X fp32 -> fp16
// ---------------------------------------------------------------------------
__global__ __launch_bounds__(256) void presplit_kernel(
    const float* __restrict__ X, f16* __restrict__ Xf) {
  size_t i = ((size_t)blockIdx.x * 256 + threadIdx.x) * 8;
  f32x4 v0 = *(const f32x4*)&X[i];
  f32x4 v1 = *(const f32x4*)&X[i + 4];
  f16x8 hv;
#pragma unroll
  for (int j = 0; j < 4; ++j) {
    hv[j] = (f16)v0[j];
    hv[j + 4] = (f16)v1[j];
  }
  *(f16x8*)&Xf[i] = hv;
}

// ---------------------------------------------------------------------------
// Transpose + convert weights -> single fp16, [f][e] layout.
// W_Q pre-scaled by log2(e) (softmax runs in exp2 domain).
// ---------------------------------------------------------------------------
__global__ __launch_bounds__(512) void wt_conv3_kernel(
    const float* __restrict__ Wq, const float* __restrict__ Wk,
    const float* __restrict__ Wv, f16* __restrict__ oq, f16* __restrict__ ok,
    f16* __restrict__ ov) {
  const float* W = blockIdx.z == 0 ? Wq : (blockIdx.z == 1 ? Wk : Wv);
  f16* o = blockIdx.z == 0 ? oq : (blockIdx.z == 1 ? ok : ov);
  const float scl = blockIdx.z == 0 ? 1.4426950408889634f : 1.0f;
  __shared__ float t[64][65];
  const int f0 = blockIdx.x * 64, e0 = blockIdx.y * 64;
  const int tx = threadIdx.x, ty = threadIdx.y;
#pragma unroll
  for (int j = 0; j < 8; ++j)
    t[ty + 8 * j][tx] = W[(size_t)(e0 + ty + 8 * j) * E_ + f0 + tx];
  __syncthreads();
#pragma unroll
  for (int j = 0; j < 8; ++j)
    o[(size_t)(f0 + ty + 8 * j) * E_ + e0 + tx] =
        (f16)(t[tx][ty + 8 * j] * scl);
}

// ---------------------------------------------------------------------------
// Fused QKV GEMM: O = X(f16) * W(f16).
// T3-minimum 2-phase this round: double-buffered LDS (64 KB), STAGE(t+1)
// issued BEFORE compute(t), single vmcnt(0)+barrier per K-iter -- stage
// latency hides under the whole compute phase (we run only 8 waves/CU, so
// intra-wave overlap matters more than in the 12-wave m97 case).
// z: 0-7 = Q ([B,H,S,D], log2e-scaled), 8-15 = K, 16-23 = V ([B,H,D,S]).
// ---------------------------------------------------------------------------
__global__ __launch_bounds__(256) void gemm_qkv_kernel(
    const f16* __restrict__ Xf,
    const f16* __restrict__ Wq, const f16* __restrict__ Wk,
    const f16* __restrict__ Wv,
    f16* __restrict__ Qf, f16* __restrict__ Kf, f16* __restrict__ Vt) {
  __shared__ f16 sA[2][128][64], sB[2][128][64];   // 64 KB
  const int bid = blockIdx.x;
  const int xcd = bid & 7, idx = bid >> 3;   // idx in [0,192)
  const int mb = xcd * 8 + idx / 24;         // [0,64)
  const int nb = idx % 24;
  const int z = nb >> 3;
  const int n0 = (nb & 7) * 128, m0 = mb * 128;
  const f16* __restrict__ Bt = z == 0 ? Wq : (z == 1 ? Wk : Wv);
  const int tid = threadIdx.x;
  const int lane = tid & 63, w = tid >> 6;
  const int wm = (w >> 1) * 64, wn = (w & 1) * 64;
  const int fr = lane & 15, fg = lane >> 4;
  f32x4 acc[4][4] = {};

#define GSTAGE(buf, k0s)                                                      \
  {                                                                           \
    _Pragma("unroll")                                                         \
    for (int i = 0; i < 4; ++i) {                                             \
      int ci = tid + i * 256;                                                 \
      int r = ci >> 3, cl = ci & 7;                                           \
      int cs = (cl ^ (r & 7)) * 8;                                            \
      gll16(Xf + (size_t)(m0 + r) * E_ + (k0s) + cs, &sA[buf][0][0] + ci * 8);\
      gll16(Bt + (size_t)(n0 + r) * E_ + (k0s) + cs, &sB[buf][0][0] + ci * 8);\
    }                                                                         \
  }

  GSTAGE(0, 0);
  asm volatile("s_waitcnt vmcnt(0)" ::: "memory");
  __builtin_amdgcn_sched_barrier(0);
  __builtin_amdgcn_s_barrier();

  for (int k0 = 0; k0 < E_; k0 += 64) {
    const int cur = (k0 >> 6) & 1;
    if (k0 + 64 < E_) GSTAGE(cur ^ 1, k0 + 64);   // hides under compute
#pragma unroll
    for (int kh2 = 0; kh2 < 2; ++kh2) {
      f16x8 ah[4];
#pragma unroll
      for (int mi = 0; mi < 4; ++mi) {
        int rA = wm + mi * 16 + fr;
        ah[mi] = *(const f16x8*)&sA[cur][rA][(((kh2 * 4 + fg) ^ (rA & 7))) * 8];
      }
#pragma unroll
      for (int ni = 0; ni < 4; ++ni) {
        int rB = wn + ni * 16 + fr;
        f16x8 bh = *(const f16x8*)&sB[cur][rB][(((kh2 * 4 + fg) ^ (rB & 7))) * 8];
#pragma unroll
        for (int mi = 0; mi < 4; ++mi)
          acc[mi][ni] = mfma16(ah[mi], bh, acc[mi][ni]);
      }
    }
    asm volatile("s_waitcnt vmcnt(0)" ::: "memory");
    __builtin_amdgcn_sched_barrier(0);
    __builtin_amdgcn_s_barrier();
  }
  if (z < 2) {
    f16* Of = z == 0 ? Qf : Kf;
#pragma unroll
    for (int mi = 0; mi < 4; ++mi)
#pragma unroll
      for (int ni = 0; ni < 4; ++ni)
#pragma unroll
        for (int r = 0; r < 4; ++r) {
          int row = m0 + wm + mi * 16 + (lane >> 4) * 4 + r;
          int col = n0 + wn + ni * 16 + fr;
          int bb = row >> 10, s = row & 1023;
          int hd = col >> 6, d = col & 63;
          Of[((size_t)(bb * H_ + hd) * S_ + s) * D_ + d] = (f16)acc[mi][ni][r];
        }
  } else {
#pragma unroll
    for (int mi = 0; mi < 4; ++mi)
#pragma unroll
      for (int ni = 0; ni < 4; ++ni) {
        int row = m0 + wm + mi * 16 + (lane >> 4) * 4;
        int col = n0 + wn + ni * 16 + fr;
        int bb = row >> 10, s = row & 1023;
        int hd = col >> 6, d = col & 63;
        f16x4 p;
#pragma unroll
        for (int r = 0; r < 4; ++r) p[r] = (f16)acc[mi][ni][r];
        *(f16x4*)&Vt[((size_t)(bb * H_ + hd) * D_ + d) * S_ + s] = p;
      }
  }
}

// ---------------------------------------------------------------------------
// Flash attention + ReLU — REVERTED to the round-11 version (132.7 µs total).
// r12 evidence: direct-from-L2 fragment reads are latency-bound (MfmaUtil 9%,
// 32B used per 128B line); LDS staging converts that latency to bandwidth.
// - 1-term fp16 QK^T; MFMA rowsum (Ol); 2-phase LDS (32KB), STAGE(t+1) at
//   iter top, vmcnt(0)+barrier at iter end; 4 blocks/CU (grid 1024);
//   exact-max chunk-0 prologue (overflow-safe), spec-exp2 + rare rescale.
// ---------------------------------------------------------------------------
__global__ __launch_bounds__(256, 4) void attn_kernel(
    const f16* __restrict__ Qf, const f16* __restrict__ Kf,
    const f16* __restrict__ Vt, float* __restrict__ out) {
  __shared__ f16 sK[2][64][64], sV[2][64][64];   // 32 KB
  const int bid = blockIdx.x;
  const int bh = (bid & 7) * 16 + (bid >> 6);    // 8 qb of one bh on one XCD
  const int qb = (bid >> 3) & 7;
  const int hd = bh & 15, bb = bh >> 4;
  const int tid = threadIdx.x;
  const int lane = tid & 63, w = tid >> 6;
  const int cq = lane & 31, h = lane >> 5;
  const int rsw = cq & 7;
  const size_t base = (size_t)bh * (S_ * D_);
  const f16* Qf_p = Qf + base;
  const f16* Kf_p = Kf + base;
  const f16* Vt_p = Vt + base;
  const int q0 = qb * 128 + w * 32;

  f16x8 qh_[4];
#pragma unroll
  for (int ks = 0; ks < 4; ++ks)
    qh_[ks] = *(const f16x8*)&Qf_p[(size_t)(q0 + cq) * D_ + ks * 16 + 8 * h];

  f16x8 ones;
#pragma unroll
  for (int j = 0; j < 8; ++j) ones[j] = (f16)1.0f;

  float m_run;
  f32x16 O[2] = {}, Ol = {};     // Ol: all-ones-A mfma rowsum (l = Ol[0])
  f16x8 pf[4];

#define STAGE(buf, kb)                                                        \
  {                                                                           \
    _Pragma("unroll")                                                         \
    for (int half = 0; half < 2; ++half) {                                    \
      int ci = tid + half * 256;                                              \
      int row = ci >> 3, cl = ci & 7;                                         \
      int cs = cl ^ (row & 7);                                                \
      gll16(Kf_p + (size_t)((kb) + row) * D_ + cs * 8, &sK[buf][0][0] + ci * 8); \
      gll16(Vt_p + (size_t)row * S_ + (kb) + cs * 8, &sV[buf][0][0] + ci * 8);   \
    }                                                                         \
  }

#define QKT(scv, bufi)                                                        \
  {                                                                           \
    _Pragma("unroll")                                                         \
    for (int f = 0; f < 2; ++f) {                                             \
      _Pragma("unroll")                                                       \
      for (int ks = 0; ks < 4; ++ks) {                                        \
        int cc = ((2 * ks + h) ^ rsw) * 8;                                    \
        f16x8 kv = *(const f16x8*)&sK[bufi][f * 32 + cq][cc];                 \
        scv[f] = mfma32(kv, qh_[ks], scv[f]);                                 \
      }                                                                       \
    }                                                                         \
  }

#define MAXTREE(pm, scv)                                                      \
  {                                                                           \
    float t4[4];                                                              \
    _Pragma("unroll")                                                         \
    for (int i = 0; i < 4; ++i) {                                             \
      float a = fmaxf(fmaxf(scv[0][i], scv[0][i + 4]),                        \
                      fmaxf(scv[0][i + 8], scv[0][i + 12]));                  \
      float b = fmaxf(fmaxf(scv[1][i], scv[1][i + 4]),                        \
                      fmaxf(scv[1][i + 8], scv[1][i + 12]));                  \
      t4[i] = fmaxf(a, b);                                                    \
    }                                                                         \
    pm = fmaxf(fmaxf(t4[0], t4[1]), fmaxf(t4[2], t4[3]));                     \
    pm = fmaxf(pm, __shfl_xor(pm, 32));                                       \
  }

#define PFBUILD(scv)                                                          \
  {                                                                           \
    _Pragma("unroll")                                                         \
    for (int f = 0; f < 2; ++f) {                                             \
      _Pragma("unroll")                                                       \
      for (int ksl = 0; ksl < 2; ++ksl) {                                     \
        int b0 = 8 * ksl;                                                     \
        int a1 = pkrtz(scv[f][b0 + 0], scv[f][b0 + 1]);                       \
        int b1 = pkrtz(scv[f][b0 + 4], scv[f][b0 + 5]);                       \
        int2v r1 = __builtin_amdgcn_permlane32_swap(a1, b1, false, false);    \
        int a2 = pkrtz(scv[f][b0 + 2], scv[f][b0 + 3]);                       \
        int b2 = pkrtz(scv[f][b0 + 6], scv[f][b0 + 7]);                       \
        int2v r2 = __builtin_amdgcn_permlane32_swap(a2, b2, false, false);    \
        int4v wd;                                                             \
        wd[0] = r1[0]; wd[1] = r2[0]; wd[2] = r1[1]; wd[3] = r2[1];           \
        pf[2 * f + ksl] = __builtin_bit_cast(f16x8, wd);                      \
      }                                                                       \
    }                                                                         \
  }

#define PVT(bufi)                                                             \
  {                                                                           \
    _Pragma("unroll")                                                         \
    for (int ks = 0; ks < 4; ++ks) {                                          \
      int cc = ((2 * ks + h) ^ rsw) * 8;                                      \
      _Pragma("unroll")                                                       \
      for (int df = 0; df < 2; ++df) {                                        \
        f16x8 vf = *(const f16x8*)&sV[bufi][df * 32 + cq][cc];                \
        O[df] = mfma32(vf, pf[ks], O[df]);                                    \
      }                                                                       \
      Ol = mfma32(ones, pf[ks], Ol);                                          \
    }                                                                         \
  }

  // ---- prologue: stage + compute chunk 0 with EXACT max (overflow-safe)
  STAGE(0, 0);
  asm volatile("s_waitcnt vmcnt(0)" ::: "memory");
  __builtin_amdgcn_sched_barrier(0);
  __builtin_amdgcn_s_barrier();
  STAGE(1, 64);                        // prefetch chunk 1 under chunk-0 work
  {
    f32x16 sc[2] = {};
    __builtin_amdgcn_s_setprio(1);
    QKT(sc, 0);
    __builtin_amdgcn_s_setprio(0);
    float pm;
    MAXTREE(pm, sc);
    m_run = pm;
#pragma unroll
    for (int f = 0; f < 2; ++f)
#pragma unroll
      for (int r = 0; r < 16; ++r)
        sc[f][r] = __builtin_amdgcn_exp2f(sc[f][r] - pm);
    PFBUILD(sc);
    __builtin_amdgcn_s_setprio(1);
    PVT(0);
    __builtin_amdgcn_s_setprio(0);
  }
  asm volatile("s_waitcnt vmcnt(0)" ::: "memory");
  __builtin_amdgcn_sched_barrier(0);
  __builtin_amdgcn_s_barrier();

  // ---- main loop, chunks 1..15: spec-exp + rare exact rescale
  for (int t = 1; t < 16; ++t) {
    const int cur = t & 1;
    if (t < 15) STAGE(cur ^ 1, (t + 1) * 64);   // hides under compute(t)

    f32x16 sc[2];
#pragma unroll
    for (int f = 0; f < 2; ++f)
#pragma unroll
      for (int r = 0; r < 16; ++r) sc[f][r] = -m_run;
    __builtin_amdgcn_s_setprio(1);
    QKT(sc, cur);
    __builtin_amdgcn_s_setprio(0);

#pragma unroll
    for (int f = 0; f < 2; ++f)
#pragma unroll
      for (int r = 0; r < 16; ++r)
        sc[f][r] = __builtin_amdgcn_exp2f(sc[f][r]);

    float pm;
    MAXTREE(pm, sc);
    if (__any(pm > 2048.f)) {
      float pmx = fmaxf(pm, 1.0f);
      float scl = 1.0f / pmx;
      m_run += __builtin_amdgcn_logf(pmx);   // v_log_f32 = log2
#pragma unroll
      for (int f = 0; f < 2; ++f)
#pragma unroll
        for (int r = 0; r < 16; ++r) sc[f][r] *= scl;
#pragma unroll
      for (int df = 0; df < 2; ++df)
#pragma unroll
        for (int i = 0; i < 16; ++i) O[df][i] *= scl;
#pragma unroll
      for (int i = 0; i < 16; ++i) Ol[i] *= scl;
    }

    PFBUILD(sc);
    __builtin_amdgcn_s_setprio(1);
    PVT(cur);
    __builtin_amdgcn_s_setprio(0);

    asm volatile("s_waitcnt vmcnt(0)" ::: "memory");
    __builtin_amdgcn_sched_barrier(0);
    __builtin_amdgcn_s_barrier();
  }

  // ---- epilogue: relu(O/l) -> fp32 [B,S,E];  l = Ol[0] (all rows equal)
  float inv = 1.0f / Ol[0];
  int s = q0 + cq;
  float* orow = out + ((size_t)bb * S_ + s) * E_ + hd * 64;
#pragma unroll
  for (int df = 0; df < 2; ++df)
#pragma unroll
    for (int g = 0; g < 4; ++g) {
      f32x4 vv;
#pragma unroll
      for (int j = 0; j < 4; ++j)
        vv[j] = fmaxf(O[df][4 * g + j] * inv, 0.f);
      *(f32x4*)&orow[df * 32 + 8 * g + 4 * h] = vv;
    }
}

// ---------------------------------------------------------------------------
// Launcher. Workspace ~70 MB:
//  Wq,Wk,Wv 3x2MB @0; Xf @6M; Qf @22M; Kf @38M; Vt @54M
// ---------------------------------------------------------------------------
extern "C" void kernel_launch(void* const* d_in, const int* in_sizes, int n_in,
                              void* d_out, int out_size, void* d_ws, size_t ws_size,
                              hipStream_t stream) {
  const float* X  = (const float*)d_in[0];
  const float* Wq = (const float*)d_in[1];
  const float* Wk = (const float*)d_in[2];
  const float* Wv = (const float*)d_in[3];
  float* out = (float*)d_out;
  char* ws = (char*)d_ws;

  const size_t WSZ = (size_t)E_ * E_ * sizeof(f16);   // 2 MB
  const size_t QSZ = (size_t)M_ * E_ * sizeof(f16);   // 16 MB
  f16* Wqf = (f16*)(ws);
  f16* Wkf = (f16*)(ws + WSZ);
  f16* Wvf = (f16*)(ws + 2 * WSZ);
  char* p = ws + 3 * WSZ;
  f16* Xf = (f16*)(p);
  f16* Qf = (f16*)(p + QSZ);
  f16* Kf = (f16*)(p + 2 * QSZ);
  f16* Vt = (f16*)(p + 3 * QSZ);

  presplit_kernel<<<4096, 256, 0, stream>>>(X, Xf);
  wt_conv3_kernel<<<dim3(16, 16, 3), dim3(64, 8), 0, stream>>>(
      Wq, Wk, Wv, Wqf, Wkf, Wvf);

  gemm_qkv_kernel<<<1536, 256, 0, stream>>>(
      Xf, Wqf, Wkf, Wvf, Qf, Kf, Vt);

  attn_kernel<<<1024, 256, 0, stream>>>(Qf, Kf, Vt, out);
}